// Round 18
// baseline (149.895 us; speedup 1.0000x reference)
//
#include <hip/hip_runtime.h>

typedef short bfrag8 __attribute__((ext_vector_type(8)));
typedef float floatx4 __attribute__((ext_vector_type(4)));
typedef float floatx16 __attribute__((ext_vector_type(16)));

#define MFMA_BF16(a, b, c) __builtin_amdgcn_mfma_f32_16x16x32_bf16((a), (b), (c), 0, 0, 0)
#define MFMA32(a, b, c) __builtin_amdgcn_mfma_f32_32x32x16_bf16((a), (b), (c), 0, 0, 0)

#define S_LEN 2048
#define D_MODEL 1024
#define NH 16
#define DK 64

__device__ __forceinline__ unsigned short f2bf(float f) {
  unsigned int u = __float_as_uint(f);
  u += 0x7fffu + ((u >> 16) & 1u);
  return (unsigned short)(u >> 16);
}

typedef const __attribute__((address_space(1))) unsigned int guint;
typedef __attribute__((address_space(3))) unsigned int luint;
__device__ __forceinline__ void gload16(const void* g, void* l) {
  __builtin_amdgcn_global_load_lds((guint*)g, (luint*)l, 16, 0, 0);
}

// ------- fused f32->bf16 conversions + mask pack (bf16), ONE launch ---------
// blocks 0..8191: cvt regions (x 4096 | wq wk wv wfc 1024 each; Wq pre-scaled
// by 0.125 = 1/sqrt(dk)). blocks 8192..8703: pack_mask.
// Mp layout: elem offset (((kt*2 + cn)*2 + hf)*2048 + q)*16 + g*4 + r
// (k = kt*64+cn*32+g*8+hf*4+r) -> attn reads 2 coalesced uint4 per iter.
__global__ __launch_bounds__(256) void cvt_pack(
    const float* __restrict__ x, const float* __restrict__ wq,
    const float* __restrict__ wk, const float* __restrict__ wv,
    const float* __restrict__ wfc, const float* __restrict__ mask,
    unsigned short* __restrict__ xb, unsigned short* __restrict__ wqb,
    unsigned short* __restrict__ wkb, unsigned short* __restrict__ wvb,
    unsigned short* __restrict__ wfb, unsigned short* __restrict__ Mp) {
  __shared__ unsigned short T[64 * 132];
  const int bid = blockIdx.x;
  const int tid = threadIdx.x;
  if (bid < 8192) {
    const float* src;
    unsigned short* dst;
    int base;
    float sc = 1.0f;
    if (bid < 4096) { src = x; dst = xb; base = bid; }
    else if (bid < 5120) { src = wq; dst = wqb; base = bid - 4096; sc = 0.125f; }
    else if (bid < 6144) { src = wk; dst = wkb; base = bid - 5120; }
    else if (bid < 7168) { src = wv; dst = wvb; base = bid - 6144; }
    else { src = wfc; dst = wfb; base = bid - 7168; }
    const int i = (base * 256 + tid) * 4;
    float4 v = *reinterpret_cast<const float4*>(src + i);
    v.x *= sc; v.y *= sc; v.z *= sc; v.w *= sc;
    uint2 p;
    p.x = (unsigned int)f2bf(v.x) | ((unsigned int)f2bf(v.y) << 16);
    p.y = (unsigned int)f2bf(v.z) | ((unsigned int)f2bf(v.w) << 16);
    *reinterpret_cast<uint2*>(dst + i) = p;
    return;
  }
  const int pb = bid - 8192;
  const int kp = pb & 15, qp = pb >> 4;  // 128-k patch, 64-q patch
#pragma unroll
  for (int it = 0; it < 8; ++it) {
    int idx = it * 256 + tid;
    int q = idx >> 5, kq = (idx & 31) * 4;
    float4 v = *reinterpret_cast<const float4*>(
        mask + (size_t)(qp * 64 + q) * 2048 + kp * 128 + kq);
    uint2 p;
    p.x = (unsigned int)f2bf(v.x) | ((unsigned int)f2bf(v.y) << 16);
    p.y = (unsigned int)f2bf(v.z) | ((unsigned int)f2bf(v.w) << 16);
    *reinterpret_cast<uint2*>(&T[q * 132 + kq]) = p;
  }
  __syncthreads();
#pragma unroll
  for (int it = 0; it < 2; ++it) {
    const int item = it * 256 + tid;
    const int q6 = item & 63, rest = item >> 6;
    const int ktl = rest >> 2, cn = (rest >> 1) & 1, hf = rest & 1;
    const int ktg = kp * 2 + ktl;
    const int base = q6 * 132 + ktl * 64 + cn * 32 + hf * 4;
    uint2 u0 = *reinterpret_cast<const uint2*>(&T[base + 0 * 8]);
    uint2 u1 = *reinterpret_cast<const uint2*>(&T[base + 1 * 8]);
    uint2 u2 = *reinterpret_cast<const uint2*>(&T[base + 2 * 8]);
    uint2 u3 = *reinterpret_cast<const uint2*>(&T[base + 3 * 8]);
    unsigned short* dst =
        Mp + ((((size_t)ktg * 2 + cn) * 2 + hf) * 2048 + (qp * 64 + q6)) * 16;
    uint4 w0, w1;
    w0.x = u0.x; w0.y = u0.y; w0.z = u1.x; w0.w = u1.y;
    w1.x = u2.x; w1.y = u2.y; w1.z = u3.x; w1.w = u3.y;
    *reinterpret_cast<uint4*>(dst) = w0;
    *reinterpret_cast<uint4*>(dst + 8) = w1;
  }
}

// ---------------- NT GEMM: C[M,N] = A[M,K] * B[N,K]^T ----------------
// WVT: z==2 (V) output written directly in transposed Vt[bh][dk][S] layout.
template <int WF32, int TN, int WVT>
__global__ __launch_bounds__(256) void gemm_nt(
    const unsigned short* __restrict__ A, const unsigned short* __restrict__ B0,
    const unsigned short* __restrict__ B1, const unsigned short* __restrict__ B2,
    unsigned short* __restrict__ C0, unsigned short* __restrict__ C1,
    unsigned short* __restrict__ C2, float* __restrict__ Cf,
    const float* __restrict__ bias) {
  constexpr int K = 1024;
  constexpr int NJ = TN / 32;  // per-wave N fragments
  __shared__ unsigned short As[2][128 * 32];
  __shared__ unsigned short Bs[2][TN * 32];
  const int z = blockIdx.z;
  const unsigned short* Bw = (z == 0) ? B0 : (z == 1) ? B1 : B2;
  unsigned short* Cb = (z == 0) ? C0 : (z == 1) ? C1 : C2;
  const int tid = threadIdx.x, lane = tid & 63, wid = tid >> 6;
  const int lr = lane & 15, lk = lane >> 4;
  const int gx = gridDim.x, nflat = gx * gridDim.y;
  int flat = blockIdx.y * gx + blockIdx.x;
  flat = (flat & 7) * (nflat >> 3) + (flat >> 3);
  const int bm = (flat / gx) * 128, bn = (flat % gx) * TN;
  const int wm = (wid >> 1) * 64, wn = (wid & 1) * (TN / 2);
  floatx4 acc[4][NJ] = {};

  const int srow = tid >> 2, scb = (tid & 3) * 16;
  const int ssw = scb ^ (((srow >> 1) & 3) << 4);  // pre-swizzled source col
  const char* gA = (const char*)A + ((size_t)(bm + srow) * K) * 2 + ssw;
  const char* gB = (const char*)Bw + ((size_t)(bn + srow) * K) * 2 + ssw;

  auto stage = [&](int buf, int k0) {
    gload16(gA + (size_t)k0 * 2, (char*)&As[buf][0] + tid * 16);
    gload16(gA + ((size_t)64 * K + k0) * 2, (char*)&As[buf][0] + 4096 + tid * 16);
    gload16(gB + (size_t)k0 * 2, (char*)&Bs[buf][0] + tid * 16);
    if constexpr (TN == 128)
      gload16(gB + ((size_t)64 * K + k0) * 2, (char*)&Bs[buf][0] + 4096 + tid * 16);
  };

  stage(0, 0);
  __syncthreads();
  int cur = 0;
  const int csw = (lk * 16) ^ (((lr >> 1) & 3) << 4);  // read-side swizzle
  for (int k0 = 0; k0 < K; k0 += 32) {
    if (k0 + 32 < K) stage(cur ^ 1, k0 + 32);
    const char* Ab = (const char*)&As[cur][0];
    const char* Bb = (const char*)&Bs[cur][0];
    bfrag8 af[4], bfr[NJ];
#pragma unroll
    for (int i = 0; i < 4; ++i)
      af[i] = *reinterpret_cast<const bfrag8*>(Ab + (wm + i * 16 + lr) * 64 + csw);
#pragma unroll
    for (int j = 0; j < NJ; ++j)
      bfr[j] = *reinterpret_cast<const bfrag8*>(Bb + (wn + j * 16 + lr) * 64 + csw);
#pragma unroll
    for (int i = 0; i < 4; ++i)
#pragma unroll
      for (int j = 0; j < NJ; ++j)
        acc[i][j] = MFMA_BF16(af[i], bfr[j], acc[i][j]);
    __syncthreads();
    cur ^= 1;
  }

  if (WVT && z == 2) {
#pragma unroll
    for (int i = 0; i < 4; ++i)
#pragma unroll
      for (int j = 0; j < NJ; ++j) {
        const int row = bm + wm + i * 16 + lk * 4;
        const int col = bn + wn + j * 16 + lr;
        uint2 pk;
        pk.x = (unsigned int)f2bf(acc[i][j][0]) |
               ((unsigned int)f2bf(acc[i][j][1]) << 16);
        pk.y = (unsigned int)f2bf(acc[i][j][2]) |
               ((unsigned int)f2bf(acc[i][j][3]) << 16);
        *reinterpret_cast<uint2*>(
            &Cb[((size_t)(row >> 11) * 1024 + col) * 2048 + (row & 2047)]) = pk;
      }
    return;
  }

#pragma unroll
  for (int i = 0; i < 4; ++i)
#pragma unroll
    for (int j = 0; j < NJ; ++j) {
      const int row = bm + wm + i * 16 + lk * 4;
      const int col = bn + wn + j * 16 + lr;
#pragma unroll
      for (int r = 0; r < 4; ++r) {
        if (WF32)
          Cf[(size_t)(row + r) * D_MODEL + col] = acc[i][j][r] + bias[col];
        else
          Cb[(size_t)(row + r) * D_MODEL + col] = f2bf(acc[i][j][r]);
      }
    }
}

// ---------------- FC GEMM: Cf = (A0 + A1) * B^T + bias ----------------------
// 64x64 tile, 2 waves, 1024 blocks. A0/A1 are the two attn k-half partials
// (bf16); summed exactly in the f32 accumulator via two MFMA chains.
__global__ __launch_bounds__(128) void gemm_fc64(
    const unsigned short* __restrict__ A0, const unsigned short* __restrict__ A1,
    const unsigned short* __restrict__ Bw, float* __restrict__ Cf,
    const float* __restrict__ bias) {
  constexpr int K = 1024;
  __shared__ unsigned short As0[2][64 * 32];
  __shared__ unsigned short As1[2][64 * 32];
  __shared__ unsigned short Bs[2][64 * 32];
  const int tid = threadIdx.x, lane = tid & 63, wid = tid >> 6;
  const int lr = lane & 15, lk = lane >> 4;
  const int gx = gridDim.x;  // 16
  int flat = blockIdx.y * gx + blockIdx.x;
  flat = (flat & 7) * 128 + (flat >> 3);
  const int bm = (flat / gx) * 64, bn = (flat % gx) * 64;
  const int wm = wid * 32;
  floatx4 acc[2][4] = {};

  const int srow = tid >> 2, scb = (tid & 3) * 16;
  const int ssw = scb ^ (((srow >> 1) & 3) << 4);
  const char* gA0 = (const char*)A0 + ((size_t)(bm + srow) * K) * 2 + ssw;
  const char* gA1 = (const char*)A1 + ((size_t)(bm + srow) * K) * 2 + ssw;
  const char* gB = (const char*)Bw + ((size_t)(bn + srow) * K) * 2 + ssw;

  auto stage = [&](int buf, int k0) {
#pragma unroll
    for (int p = 0; p < 2; ++p) {
      gload16(gA0 + ((size_t)p * 32 * K + k0) * 2,
              (char*)&As0[buf][0] + p * 2048 + tid * 16);
      gload16(gA1 + ((size_t)p * 32 * K + k0) * 2,
              (char*)&As1[buf][0] + p * 2048 + tid * 16);
      gload16(gB + ((size_t)p * 32 * K + k0) * 2,
              (char*)&Bs[buf][0] + p * 2048 + tid * 16);
    }
  };

  stage(0, 0);
  __syncthreads();
  int cur = 0;
  const int csw = (lk * 16) ^ (((lr >> 1) & 3) << 4);
  for (int k0 = 0; k0 < K; k0 += 32) {
    if (k0 + 32 < K) stage(cur ^ 1, k0 + 32);
    const char* Ab0 = (const char*)&As0[cur][0];
    const char* Ab1 = (const char*)&As1[cur][0];
    const char* Bb = (const char*)&Bs[cur][0];
    bfrag8 af0[2], af1[2], bfr[4];
#pragma unroll
    for (int i = 0; i < 2; ++i) {
      af0[i] = *reinterpret_cast<const bfrag8*>(Ab0 + (wm + i * 16 + lr) * 64 + csw);
      af1[i] = *reinterpret_cast<const bfrag8*>(Ab1 + (wm + i * 16 + lr) * 64 + csw);
    }
#pragma unroll
    for (int j = 0; j < 4; ++j)
      bfr[j] = *reinterpret_cast<const bfrag8*>(Bb + (j * 16 + lr) * 64 + csw);
#pragma unroll
    for (int i = 0; i < 2; ++i)
#pragma unroll
      for (int j = 0; j < 4; ++j) {
        acc[i][j] = MFMA_BF16(af0[i], bfr[j], acc[i][j]);
        acc[i][j] = MFMA_BF16(af1[i], bfr[j], acc[i][j]);
      }
    __syncthreads();
    cur ^= 1;
  }

#pragma unroll
  for (int i = 0; i < 2; ++i)
#pragma unroll
    for (int j = 0; j < 4; ++j) {
      const int row = bm + wm + i * 16 + lk * 4;
      const int col = bn + j * 16 + lr;
#pragma unroll
      for (int r = 0; r < 4; ++r)
        Cf[(size_t)(row + r) * D_MODEL + col] = acc[i][j][r] + bias[col];
    }
}

// ---------------- fused relu-attention (decoupled k-half blocks) -------------
// Block = one (b,h,q0,cn): 128 thr = 2 waves (qgrp), each 32 q x this block's
// 32-k half per tile. 2048 blocks x 24 KB LDS -> 6 blocks/CU, 12 waves/CU,
// 2-wave barrier scope, k-halves fully independent. Partial O^T (this k-half)
// written bf16 to O0/O1; the FC GEMM sums them via a second MFMA chain.
// K-half staged per block (4 KB); V tile staged fully (8 KB, half consumed).
#define ATTN_BODY(KT, MKU, MKL)                                                 \
  {                                                                             \
    const int kt = (KT);                                                        \
    if (kt + 1 < NT) {                                                          \
      stage(cur ^ 1, kt + 1);                                                   \
      const uint4* m4 = reinterpret_cast<const uint4*>(                         \
          mpb + (size_t)(kt + 1) * 131072);                                     \
      MKL[0] = m4[0]; MKL[1] = m4[1];                                           \
    }                                                                           \
    floatx16 sacc;                                                              \
    sacc[0] = __uint_as_float(MKU[0].x << 16);                                  \
    sacc[1] = __uint_as_float(MKU[0].x & 0xffff0000u);                          \
    sacc[2] = __uint_as_float(MKU[0].y << 16);                                  \
    sacc[3] = __uint_as_float(MKU[0].y & 0xffff0000u);                          \
    sacc[4] = __uint_as_float(MKU[0].z << 16);                                  \
    sacc[5] = __uint_as_float(MKU[0].z & 0xffff0000u);                          \
    sacc[6] = __uint_as_float(MKU[0].w << 16);                                  \
    sacc[7] = __uint_as_float(MKU[0].w & 0xffff0000u);                          \
    sacc[8] = __uint_as_float(MKU[1].x << 16);                                  \
    sacc[9] = __uint_as_float(MKU[1].x & 0xffff0000u);                          \
    sacc[10] = __uint_as_float(MKU[1].y << 16);                                 \
    sacc[11] = __uint_as_float(MKU[1].y & 0xffff0000u);                         \
    sacc[12] = __uint_as_float(MKU[1].z << 16);                                 \
    sacc[13] = __uint_as_float(MKU[1].z & 0xffff0000u);                         \
    sacc[14] = __uint_as_float(MKU[1].w << 16);                                 \
    sacc[15] = __uint_as_float(MKU[1].w & 0xffff0000u);                         \
    const char* Kb = (const char*)&Kt[cur][0];                                  \
    __builtin_amdgcn_s_setprio(1);                                              \
    _Pragma("unroll") for (int ks = 0; ks < 4; ++ks) {                          \
      bfrag8 kf = *reinterpret_cast<const bfrag8*>(                             \
          Kb + lq * 128 + (((ks * 16 + hf * 8) * 2) ^ swzr));                   \
      sacc = MFMA32(kf, qf[ks], sacc);                                          \
    }                                                                           \
    __builtin_amdgcn_s_setprio(0);                                              \
    float p[16];                                                                \
    _Pragma("unroll") for (int i = 0; i < 16; ++i) p[i] = fmaxf(sacc[i], 0.f);  \
    unsigned int a0, a1, b0, b1, a2, a3, b2, b3;                                \
    asm("v_cvt_pk_bf16_f32 %0, %1, %2" : "=v"(a0) : "v"(p[0]), "v"(p[1]));      \
    asm("v_cvt_pk_bf16_f32 %0, %1, %2" : "=v"(a1) : "v"(p[2]), "v"(p[3]));      \
    asm("v_cvt_pk_bf16_f32 %0, %1, %2" : "=v"(b0) : "v"(p[4]), "v"(p[5]));      \
    asm("v_cvt_pk_bf16_f32 %0, %1, %2" : "=v"(b1) : "v"(p[6]), "v"(p[7]));      \
    asm("v_cvt_pk_bf16_f32 %0, %1, %2" : "=v"(a2) : "v"(p[8]), "v"(p[9]));      \
    asm("v_cvt_pk_bf16_f32 %0, %1, %2" : "=v"(a3) : "v"(p[10]), "v"(p[11]));    \
    asm("v_cvt_pk_bf16_f32 %0, %1, %2" : "=v"(b2) : "v"(p[12]), "v"(p[13]));    \
    asm("v_cvt_pk_bf16_f32 %0, %1, %2" : "=v"(b3) : "v"(p[14]), "v"(p[15]));    \
    asm("v_permlane32_swap_b32 %0, %1" : "+v"(a0), "+v"(b0));                   \
    asm("v_permlane32_swap_b32 %0, %1" : "+v"(a1), "+v"(b1));                   \
    asm("v_permlane32_swap_b32 %0, %1" : "+v"(a2), "+v"(b2));                   \
    asm("v_permlane32_swap_b32 %0, %1" : "+v"(a3), "+v"(b3));                   \
    uint4 u0, u1;                                                               \
    u0.x = a0; u0.y = a1; u0.z = b0; u0.w = b1;                                 \
    u1.x = a2; u1.y = a3; u1.z = b2; u1.w = b3;                                 \
    bfrag8 pf0 = *reinterpret_cast<bfrag8*>(&u0);                               \
    bfrag8 pf1 = *reinterpret_cast<bfrag8*>(&u1);                               \
    const char* Vb = (const char*)&Vl[cur][0];                                  \
    __builtin_amdgcn_s_setprio(1);                                              \
    _Pragma("unroll") for (int d = 0; d < 2; ++d) {                             \
      bfrag8 vb0 = *reinterpret_cast<const bfrag8*>(                            \
          Vb + (d * 32 + lq) * 128 +                                            \
          ((((cn * 2 + 0) * 16 + hf * 8) * 2) ^ swzr));                         \
      oacc[d] = MFMA32(vb0, pf0, oacc[d]);                                      \
      bfrag8 vb1 = *reinterpret_cast<const bfrag8*>(                            \
          Vb + (d * 32 + lq) * 128 +                                            \
          ((((cn * 2 + 1) * 16 + hf * 8) * 2) ^ swzr));                         \
      oacc[d] = MFMA32(vb1, pf1, oacc[d]);                                      \
    }                                                                           \
    __builtin_amdgcn_s_setprio(0);                                              \
    __syncthreads();                                                            \
    cur ^= 1;                                                                   \
  }

__global__ __launch_bounds__(128, 3) void attn_relu(
    const unsigned short* __restrict__ Q, const unsigned short* __restrict__ Kg,
    const unsigned short* __restrict__ Vt, const unsigned short* __restrict__ Mp,
    unsigned short* __restrict__ O0, unsigned short* __restrict__ O1) {
  __shared__ unsigned short Kt[2][32 * 64];  // K-half [32 k][64 d] 8 KB
  __shared__ unsigned short Vl[2][64 * 64];  // V [64 d][64 s] 16 KB
  const int tid = threadIdx.x, lane = tid & 63, qgrp = tid >> 6;
  const int lq = lane & 31, hf = lane >> 5;
  // XCD swizzle over 2048 blocks (x=q-tile 32, y=bh 32, z=cn 2); 2048%8==0.
  int flat = (blockIdx.z * 32 + blockIdx.y) * 32 + blockIdx.x;
  flat = (flat & 7) * 256 + (flat >> 3);
  const int cn = flat >> 10, bh = (flat >> 5) & 31, q0 = (flat & 31) * 64;
  const int b = bh >> 4, hh = bh & 15;
  const int qg = q0 + qgrp * 32 + lq;  // this lane's q row

  // Q B-fragments (col=q, k-elems d = ks*16 + hf*8 + i)
  const unsigned short* qptr = Q + (size_t)(b * S_LEN + qg) * D_MODEL + hh * DK;
  bfrag8 qf[4];
#pragma unroll
  for (int ks = 0; ks < 4; ++ks)
    qf[ks] = *reinterpret_cast<const bfrag8*>(qptr + ks * 16 + hf * 8);

  // staging (128 threads).  K-half: 32 rows x 8 chunks = 256 items (2/thread);
  // V: 64 rows x 8 chunks = 512 items (4/thread). swz(r)=((r&7)<<4)^(((r>>3)&1)<<5)
  const int krow = tid >> 2, kcb = (tid & 3) * 2;  // 2 consecutive chunk-pairs? no:
  // item a = it*128 + tid -> row a>>3? use per-it formulas below instead.
  const unsigned short* mpb =
      Mp + ((size_t)(cn * 2 + hf) * 2048 + qg) * 16;
  const int swzr = ((lq & 7) << 4) ^ (((lq >> 3) & 1) << 5);  // read-side

  const char* kgB = (const char*)Kg + ((size_t)(b * S_LEN)) * 2048 + hh * 128;
  const char* vgB = (const char*)Vt + (size_t)bh * (DK * S_LEN * 2);

  floatx16 oacc[2] = {};

  auto stage = [&](int buf, int kt) {
    // K-half: rows kt*64 + cn*32 + r, r = local row
#pragma unroll
    for (int it = 0; it < 2; ++it) {
      const int a = it * 128 + tid;
      const int r = a >> 3, c = (a & 7) * 16;
      const int sw = c ^ ((r & 7) << 4) ^ (((r >> 3) & 1) << 5);
      gload16(kgB + (size_t)(kt * 64 + cn * 32 + r) * 2048 + sw,
              (char*)&Kt[buf][0] + a * 16);
    }
    // V full tile: rows r (d), cols kt*128 bytes
#pragma unroll
    for (int it = 0; it < 4; ++it) {
      const int a = it * 128 + tid;
      const int r = a >> 3, c = (a & 7) * 16;
      const int sw = c ^ ((r & 7) << 4) ^ (((r >> 3) & 1) << 5);
      gload16(vgB + (size_t)r * (S_LEN * 2) + (size_t)kt * 128 + sw,
              (char*)&Vl[buf][0] + a * 16);
    }
  };

  stage(0, 0);
  uint4 mkA[2], mkB[2];
  {
    const uint4* m4 = reinterpret_cast<const uint4*>(mpb);
    mkA[0] = m4[0]; mkA[1] = m4[1];
  }
  __syncthreads();

  int cur = 0;
  constexpr int NT = S_LEN / 64;
  for (int kt2 = 0; kt2 < NT; kt2 += 2) {
    ATTN_BODY(kt2, mkA, mkB);
    ATTN_BODY(kt2 + 1, mkB, mkA);
  }

  // ---- write partial O (bf16) for this k-half; FC sums O0 + O1.
  unsigned short* Opc = (cn == 0) ? O0 : O1;
  const size_t obase = (size_t)(b * S_LEN + qg) * D_MODEL + hh * DK;
#pragma unroll
  for (int d = 0; d < 2; ++d)
#pragma unroll
    for (int g = 0; g < 4; ++g) {
      uint2 pk;
      pk.x = (unsigned int)f2bf(oacc[d][4 * g + 0]) |
             ((unsigned int)f2bf(oacc[d][4 * g + 1]) << 16);
      pk.y = (unsigned int)f2bf(oacc[d][4 * g + 2]) |
             ((unsigned int)f2bf(oacc[d][4 * g + 3]) << 16);
      *reinterpret_cast<uint2*>(&Opc[obase + d * 32 + 8 * g + 4 * hf]) = pk;
    }
}

extern "C" void kernel_launch(void* const* d_in, const int* in_sizes, int n_in,
                              void* d_out, int out_size, void* d_ws, size_t ws_size,
                              hipStream_t stream) {
  const float* x = (const float*)d_in[0];
  const float* mask = (const float*)d_in[1];
  const float* Wq = (const float*)d_in[2];
  const float* Wk = (const float*)d_in[3];
  const float* Wv = (const float*)d_in[4];
  const float* Wfc = (const float*)d_in[5];
  const float* bfc = (const float*)d_in[6];
  float* out = (float*)d_out;

  char* ws = (char*)d_ws;
  const size_t MB = 1u << 20;
  unsigned short* xb = (unsigned short*)(ws + 0 * MB);     // 8 MB (reused as O0)
  unsigned short* Wqb = (unsigned short*)(ws + 8 * MB);    // 2 MB
  unsigned short* Wkb = (unsigned short*)(ws + 10 * MB);   // 2 MB
  unsigned short* Wvb = (unsigned short*)(ws + 12 * MB);   // 2 MB
  unsigned short* Wfb = (unsigned short*)(ws + 14 * MB);   // 2 MB
  unsigned short* Qw = (unsigned short*)(ws + 16 * MB);    // 8 MB
  unsigned short* Kw = (unsigned short*)(ws + 24 * MB);    // 8 MB
  unsigned short* Vtw = (unsigned short*)(ws + 32 * MB);   // 8 MB (transposed V)
  unsigned short* O1w = (unsigned short*)(ws + 40 * MB);   // 8 MB partial O (cn=1)
  unsigned short* Mpw = (unsigned short*)(ws + 48 * MB);   // 8 MB packed mask
  unsigned short* O0w = xb;  // attn runs after QKV GEMMs; xb is dead by then

  cvt_pack<<<8704, 256, 0, stream>>>(x, Wq, Wk, Wv, Wfc, mask,
                                     xb, Wqb, Wkb, Wvb, Wfb, Mpw);

  gemm_nt<0, 128, 1><<<dim3(D_MODEL / 128, (2 * S_LEN) / 128, 3), 256, 0, stream>>>(
      xb, Wqb, Wkb, Wvb, Qw, Kw, Vtw, nullptr, nullptr);

  attn_relu<<<dim3(S_LEN / 64, 32, 2), 128, 0, stream>>>(Qw, Kw, Vtw, Mpw,
                                                         O0w, O1w);

  gemm_fc64<<<dim3(D_MODEL / 64, (2 * S_LEN) / 64), 128, 0, stream>>>(
      O0w, O1w, Wfb, out, bfc);
}

// Round 19
// 138.411 us; speedup vs baseline: 1.0830x; 1.0830x over previous
//
#include <hip/hip_runtime.h>

typedef short bfrag8 __attribute__((ext_vector_type(8)));
typedef float floatx4 __attribute__((ext_vector_type(4)));
typedef float floatx16 __attribute__((ext_vector_type(16)));

#define MFMA_BF16(a, b, c) __builtin_amdgcn_mfma_f32_16x16x32_bf16((a), (b), (c), 0, 0, 0)
#define MFMA32(a, b, c) __builtin_amdgcn_mfma_f32_32x32x16_bf16((a), (b), (c), 0, 0, 0)

#define S_LEN 2048
#define D_MODEL 1024
#define NH 16
#define DK 64

__device__ __forceinline__ unsigned short f2bf(float f) {
  unsigned int u = __float_as_uint(f);
  u += 0x7fffu + ((u >> 16) & 1u);
  return (unsigned short)(u >> 16);
}

typedef const __attribute__((address_space(1))) unsigned int guint;
typedef __attribute__((address_space(3))) unsigned int luint;
__device__ __forceinline__ void gload16(const void* g, void* l) {
  __builtin_amdgcn_global_load_lds((guint*)g, (luint*)l, 16, 0, 0);
}

// ------- fused f32->bf16 conversions + mask pack (bf16), ONE launch ---------
// blocks 0..8191: cvt regions (x 4096 | wq wk wv wfc 1024 each; Wq pre-scaled
// by 0.125 = 1/sqrt(dk)). blocks 8192..8703: pack_mask.
// Mp layout: elem offset (((kt*2 + cn)*2 + hf)*2048 + q)*16 + g*4 + r
// (k = kt*64+cn*32+g*8+hf*4+r) -> attn reads 2 coalesced uint4 per iter.
__global__ __launch_bounds__(256) void cvt_pack(
    const float* __restrict__ x, const float* __restrict__ wq,
    const float* __restrict__ wk, const float* __restrict__ wv,
    const float* __restrict__ wfc, const float* __restrict__ mask,
    unsigned short* __restrict__ xb, unsigned short* __restrict__ wqb,
    unsigned short* __restrict__ wkb, unsigned short* __restrict__ wvb,
    unsigned short* __restrict__ wfb, unsigned short* __restrict__ Mp) {
  __shared__ unsigned short T[64 * 132];
  const int bid = blockIdx.x;
  const int tid = threadIdx.x;
  if (bid < 8192) {
    const float* src;
    unsigned short* dst;
    int base;
    float sc = 1.0f;
    if (bid < 4096) { src = x; dst = xb; base = bid; }
    else if (bid < 5120) { src = wq; dst = wqb; base = bid - 4096; sc = 0.125f; }
    else if (bid < 6144) { src = wk; dst = wkb; base = bid - 5120; }
    else if (bid < 7168) { src = wv; dst = wvb; base = bid - 6144; }
    else { src = wfc; dst = wfb; base = bid - 7168; }
    const int i = (base * 256 + tid) * 4;
    float4 v = *reinterpret_cast<const float4*>(src + i);
    v.x *= sc; v.y *= sc; v.z *= sc; v.w *= sc;
    uint2 p;
    p.x = (unsigned int)f2bf(v.x) | ((unsigned int)f2bf(v.y) << 16);
    p.y = (unsigned int)f2bf(v.z) | ((unsigned int)f2bf(v.w) << 16);
    *reinterpret_cast<uint2*>(dst + i) = p;
    return;
  }
  const int pb = bid - 8192;
  const int kp = pb & 15, qp = pb >> 4;  // 128-k patch, 64-q patch
#pragma unroll
  for (int it = 0; it < 8; ++it) {
    int idx = it * 256 + tid;
    int q = idx >> 5, kq = (idx & 31) * 4;
    float4 v = *reinterpret_cast<const float4*>(
        mask + (size_t)(qp * 64 + q) * 2048 + kp * 128 + kq);
    uint2 p;
    p.x = (unsigned int)f2bf(v.x) | ((unsigned int)f2bf(v.y) << 16);
    p.y = (unsigned int)f2bf(v.z) | ((unsigned int)f2bf(v.w) << 16);
    *reinterpret_cast<uint2*>(&T[q * 132 + kq]) = p;
  }
  __syncthreads();
#pragma unroll
  for (int it = 0; it < 2; ++it) {
    const int item = it * 256 + tid;
    const int q6 = item & 63, rest = item >> 6;
    const int ktl = rest >> 2, cn = (rest >> 1) & 1, hf = rest & 1;
    const int ktg = kp * 2 + ktl;
    const int base = q6 * 132 + ktl * 64 + cn * 32 + hf * 4;
    uint2 u0 = *reinterpret_cast<const uint2*>(&T[base + 0 * 8]);
    uint2 u1 = *reinterpret_cast<const uint2*>(&T[base + 1 * 8]);
    uint2 u2 = *reinterpret_cast<const uint2*>(&T[base + 2 * 8]);
    uint2 u3 = *reinterpret_cast<const uint2*>(&T[base + 3 * 8]);
    unsigned short* dst =
        Mp + ((((size_t)ktg * 2 + cn) * 2 + hf) * 2048 + (qp * 64 + q6)) * 16;
    uint4 w0, w1;
    w0.x = u0.x; w0.y = u0.y; w0.z = u1.x; w0.w = u1.y;
    w1.x = u2.x; w1.y = u2.y; w1.z = u3.x; w1.w = u3.y;
    *reinterpret_cast<uint4*>(dst) = w0;
    *reinterpret_cast<uint4*>(dst + 8) = w1;
  }
}

// ---------------- NT GEMM: C[M,N] = A[M,K] * B[N,K]^T ----------------
// WVT: z==2 (V) output written directly in transposed Vt[bh][dk][S] layout.
// XCD-aware block swizzle (T1): per z-slice, contiguous flats -> one XCD.
// TN=64 -> 1536 blocks (6 blocks/CU) for the merged QKV launch.
template <int WF32, int TN, int WVT>
__global__ __launch_bounds__(256) void gemm_nt(
    const unsigned short* __restrict__ A, const unsigned short* __restrict__ B0,
    const unsigned short* __restrict__ B1, const unsigned short* __restrict__ B2,
    unsigned short* __restrict__ C0, unsigned short* __restrict__ C1,
    unsigned short* __restrict__ C2, float* __restrict__ Cf,
    const float* __restrict__ bias) {
  constexpr int K = 1024;
  constexpr int NJ = TN / 32;  // per-wave N fragments
  __shared__ unsigned short As[2][128 * 32];
  __shared__ unsigned short Bs[2][TN * 32];
  const int z = blockIdx.z;
  const unsigned short* Bw = (z == 0) ? B0 : (z == 1) ? B1 : B2;
  unsigned short* Cb = (z == 0) ? C0 : (z == 1) ? C1 : C2;
  const int tid = threadIdx.x, lane = tid & 63, wid = tid >> 6;
  const int lr = lane & 15, lk = lane >> 4;
  const int gx = gridDim.x, nflat = gx * gridDim.y;
  int flat = blockIdx.y * gx + blockIdx.x;
  flat = (flat & 7) * (nflat >> 3) + (flat >> 3);
  const int bm = (flat / gx) * 128, bn = (flat % gx) * TN;
  const int wm = (wid >> 1) * 64, wn = (wid & 1) * (TN / 2);
  floatx4 acc[4][NJ] = {};

  const int srow = tid >> 2, scb = (tid & 3) * 16;
  const int ssw = scb ^ (((srow >> 1) & 3) << 4);  // pre-swizzled source col
  const char* gA = (const char*)A + ((size_t)(bm + srow) * K) * 2 + ssw;
  const char* gB = (const char*)Bw + ((size_t)(bn + srow) * K) * 2 + ssw;

  auto stage = [&](int buf, int k0) {
    gload16(gA + (size_t)k0 * 2, (char*)&As[buf][0] + tid * 16);
    gload16(gA + ((size_t)64 * K + k0) * 2, (char*)&As[buf][0] + 4096 + tid * 16);
    gload16(gB + (size_t)k0 * 2, (char*)&Bs[buf][0] + tid * 16);
    if constexpr (TN == 128)
      gload16(gB + ((size_t)64 * K + k0) * 2, (char*)&Bs[buf][0] + 4096 + tid * 16);
  };

  stage(0, 0);
  __syncthreads();
  int cur = 0;
  const int csw = (lk * 16) ^ (((lr >> 1) & 3) << 4);  // read-side swizzle
  for (int k0 = 0; k0 < K; k0 += 32) {
    if (k0 + 32 < K) stage(cur ^ 1, k0 + 32);
    const char* Ab = (const char*)&As[cur][0];
    const char* Bb = (const char*)&Bs[cur][0];
    bfrag8 af[4], bfr[NJ];
#pragma unroll
    for (int i = 0; i < 4; ++i)
      af[i] = *reinterpret_cast<const bfrag8*>(Ab + (wm + i * 16 + lr) * 64 + csw);
#pragma unroll
    for (int j = 0; j < NJ; ++j)
      bfr[j] = *reinterpret_cast<const bfrag8*>(Bb + (wn + j * 16 + lr) * 64 + csw);
#pragma unroll
    for (int i = 0; i < 4; ++i)
#pragma unroll
      for (int j = 0; j < NJ; ++j)
        acc[i][j] = MFMA_BF16(af[i], bfr[j], acc[i][j]);
    __syncthreads();
    cur ^= 1;
  }

  if (WVT && z == 2) {
#pragma unroll
    for (int i = 0; i < 4; ++i)
#pragma unroll
      for (int j = 0; j < NJ; ++j) {
        const int row = bm + wm + i * 16 + lk * 4;
        const int col = bn + wn + j * 16 + lr;
        uint2 pk;
        pk.x = (unsigned int)f2bf(acc[i][j][0]) |
               ((unsigned int)f2bf(acc[i][j][1]) << 16);
        pk.y = (unsigned int)f2bf(acc[i][j][2]) |
               ((unsigned int)f2bf(acc[i][j][3]) << 16);
        *reinterpret_cast<uint2*>(
            &Cb[((size_t)(row >> 11) * 1024 + col) * 2048 + (row & 2047)]) = pk;
      }
    return;
  }

#pragma unroll
  for (int i = 0; i < 4; ++i)
#pragma unroll
    for (int j = 0; j < NJ; ++j) {
      const int row = bm + wm + i * 16 + lk * 4;
      const int col = bn + wn + j * 16 + lr;
#pragma unroll
      for (int r = 0; r < 4; ++r) {
        if (WF32)
          Cf[(size_t)(row + r) * D_MODEL + col] = acc[i][j][r] + bias[col];
        else
          Cb[(size_t)(row + r) * D_MODEL + col] = f2bf(acc[i][j][r]);
      }
    }
}

// ---------------- FC GEMM: 64x64 tile, 2 waves, 1024 blocks (4/CU) ----------
__global__ __launch_bounds__(128) void gemm_fc64(
    const unsigned short* __restrict__ A, const unsigned short* __restrict__ Bw,
    float* __restrict__ Cf, const float* __restrict__ bias) {
  constexpr int K = 1024;
  __shared__ unsigned short As[2][64 * 32];
  __shared__ unsigned short Bs[2][64 * 32];
  const int tid = threadIdx.x, lane = tid & 63, wid = tid >> 6;
  const int lr = lane & 15, lk = lane >> 4;
  const int gx = gridDim.x;  // 16
  int flat = blockIdx.y * gx + blockIdx.x;
  flat = (flat & 7) * 128 + (flat >> 3);
  const int bm = (flat / gx) * 64, bn = (flat % gx) * 64;
  const int wm = wid * 32;
  floatx4 acc[2][4] = {};

  const int srow = tid >> 2, scb = (tid & 3) * 16;
  const int ssw = scb ^ (((srow >> 1) & 3) << 4);
  const char* gA = (const char*)A + ((size_t)(bm + srow) * K) * 2 + ssw;
  const char* gB = (const char*)Bw + ((size_t)(bn + srow) * K) * 2 + ssw;

  auto stage = [&](int buf, int k0) {
#pragma unroll
    for (int p = 0; p < 2; ++p) {
      gload16(gA + ((size_t)p * 32 * K + k0) * 2,
              (char*)&As[buf][0] + p * 2048 + tid * 16);
      gload16(gB + ((size_t)p * 32 * K + k0) * 2,
              (char*)&Bs[buf][0] + p * 2048 + tid * 16);
    }
  };

  stage(0, 0);
  __syncthreads();
  int cur = 0;
  const int csw = (lk * 16) ^ (((lr >> 1) & 3) << 4);
  for (int k0 = 0; k0 < K; k0 += 32) {
    if (k0 + 32 < K) stage(cur ^ 1, k0 + 32);
    const char* Ab = (const char*)&As[cur][0];
    const char* Bb = (const char*)&Bs[cur][0];
    bfrag8 af[2], bfr[4];
#pragma unroll
    for (int i = 0; i < 2; ++i)
      af[i] = *reinterpret_cast<const bfrag8*>(Ab + (wm + i * 16 + lr) * 64 + csw);
#pragma unroll
    for (int j = 0; j < 4; ++j)
      bfr[j] = *reinterpret_cast<const bfrag8*>(Bb + (j * 16 + lr) * 64 + csw);
#pragma unroll
    for (int i = 0; i < 2; ++i)
#pragma unroll
      for (int j = 0; j < 4; ++j)
        acc[i][j] = MFMA_BF16(af[i], bfr[j], acc[i][j]);
    __syncthreads();
    cur ^= 1;
  }

#pragma unroll
  for (int i = 0; i < 2; ++i)
#pragma unroll
    for (int j = 0; j < 4; ++j) {
      const int row = bm + wm + i * 16 + lk * 4;
      const int col = bn + j * 16 + lr;
#pragma unroll
      for (int r = 0; r < 4; ++r)
        Cf[(size_t)(row + r) * D_MODEL + col] = acc[i][j][r] + bias[col];
    }
}

// ---------------- fused relu-attention (R15: 4 waves + mask prefetch) --------
// Block = one (b,h) x 64 q; 4 waves = 2 q-groups x 2 k-halves (cn). Grid 1024
// (4 blocks/CU). Mask for kt+1 loads (2 coalesced uint4) while kt computes;
// the end-of-iter barrier drains vmcnt, so the C-init consumes ready regs.
// x2-unrolled bodies with named mask sets (no copies, no runtime reg index).
#define ATTN_BODY(KT, MKU, MKL)                                                 \
  {                                                                             \
    const int kt = (KT);                                                        \
    if (kt + 1 < NT) {                                                          \
      stage(cur ^ 1, kt + 1);                                                   \
      const uint4* m4 = reinterpret_cast<const uint4*>(                         \
          mpb + (size_t)(kt + 1) * 131072);                                     \
      MKL[0] = m4[0]; MKL[1] = m4[1];                                           \
    }                                                                           \
    /* ---- S^T = mask + K^T Q (mask as MFMA C-init; scale folded into Q) */    \
    floatx16 sacc;                                                              \
    sacc[0] = __uint_as_float(MKU[0].x << 16);                                  \
    sacc[1] = __uint_as_float(MKU[0].x & 0xffff0000u);                          \
    sacc[2] = __uint_as_float(MKU[0].y << 16);                                  \
    sacc[3] = __uint_as_float(MKU[0].y & 0xffff0000u);                          \
    sacc[4] = __uint_as_float(MKU[0].z << 16);                                  \
    sacc[5] = __uint_as_float(MKU[0].z & 0xffff0000u);                          \
    sacc[6] = __uint_as_float(MKU[0].w << 16);                                  \
    sacc[7] = __uint_as_float(MKU[0].w & 0xffff0000u);                          \
    sacc[8] = __uint_as_float(MKU[1].x << 16);                                  \
    sacc[9] = __uint_as_float(MKU[1].x & 0xffff0000u);                          \
    sacc[10] = __uint_as_float(MKU[1].y << 16);                                 \
    sacc[11] = __uint_as_float(MKU[1].y & 0xffff0000u);                         \
    sacc[12] = __uint_as_float(MKU[1].z << 16);                                 \
    sacc[13] = __uint_as_float(MKU[1].z & 0xffff0000u);                         \
    sacc[14] = __uint_as_float(MKU[1].w << 16);                                 \
    sacc[15] = __uint_as_float(MKU[1].w & 0xffff0000u);                         \
    const char* Kb = (const char*)&KV[cur][0][0];                               \
    __builtin_amdgcn_s_setprio(1);                                              \
    _Pragma("unroll") for (int ks = 0; ks < 4; ++ks) {                          \
      bfrag8 kf = *reinterpret_cast<const bfrag8*>(                             \
          Kb + (cn * 32 + lq) * 128 + (((ks * 16 + hf * 8) * 2) ^ swzr));       \
      sacc = MFMA32(kf, qf[ks], sacc);                                          \
    }                                                                           \
    __builtin_amdgcn_s_setprio(0);                                              \
    /* ---- relu -> bf16 -> permlane32_swap (P fully in registers) */           \
    float p[16];                                                                \
    _Pragma("unroll") for (int i = 0; i < 16; ++i) p[i] = fmaxf(sacc[i], 0.f);  \
    unsigned int a0, a1, b0, b1, a2, a3, b2, b3;                                \
    asm("v_cvt_pk_bf16_f32 %0, %1, %2" : "=v"(a0) : "v"(p[0]), "v"(p[1]));      \
    asm("v_cvt_pk_bf16_f32 %0, %1, %2" : "=v"(a1) : "v"(p[2]), "v"(p[3]));      \
    asm("v_cvt_pk_bf16_f32 %0, %1, %2" : "=v"(b0) : "v"(p[4]), "v"(p[5]));      \
    asm("v_cvt_pk_bf16_f32 %0, %1, %2" : "=v"(b1) : "v"(p[6]), "v"(p[7]));      \
    asm("v_cvt_pk_bf16_f32 %0, %1, %2" : "=v"(a2) : "v"(p[8]), "v"(p[9]));      \
    asm("v_cvt_pk_bf16_f32 %0, %1, %2" : "=v"(a3) : "v"(p[10]), "v"(p[11]));    \
    asm("v_cvt_pk_bf16_f32 %0, %1, %2" : "=v"(b2) : "v"(p[12]), "v"(p[13]));    \
    asm("v_cvt_pk_bf16_f32 %0, %1, %2" : "=v"(b3) : "v"(p[14]), "v"(p[15]));    \
    asm("v_permlane32_swap_b32 %0, %1" : "+v"(a0), "+v"(b0));                   \
    asm("v_permlane32_swap_b32 %0, %1" : "+v"(a1), "+v"(b1));                   \
    asm("v_permlane32_swap_b32 %0, %1" : "+v"(a2), "+v"(b2));                   \
    asm("v_permlane32_swap_b32 %0, %1" : "+v"(a3), "+v"(b3));                   \
    uint4 u0, u1;                                                               \
    u0.x = a0; u0.y = a1; u0.z = b0; u0.w = b1;                                 \
    u1.x = a2; u1.y = a3; u1.z = b2; u1.w = b3;                                 \
    bfrag8 pf0 = *reinterpret_cast<bfrag8*>(&u0);                               \
    bfrag8 pf1 = *reinterpret_cast<bfrag8*>(&u1);                               \
    const char* Vb = (const char*)&KV[cur][1][0];                               \
    __builtin_amdgcn_s_setprio(1);                                              \
    _Pragma("unroll") for (int d = 0; d < 2; ++d) {                             \
      bfrag8 vb0 = *reinterpret_cast<const bfrag8*>(                            \
          Vb + (d * 32 + lq) * 128 +                                            \
          ((((cn * 2 + 0) * 16 + hf * 8) * 2) ^ swzr));                         \
      oacc[d] = MFMA32(vb0, pf0, oacc[d]);                                      \
      bfrag8 vb1 = *reinterpret_cast<const bfrag8*>(                            \
          Vb + (d * 32 + lq) * 128 +                                            \
          ((((cn * 2 + 1) * 16 + hf * 8) * 2) ^ swzr));                         \
      oacc[d] = MFMA32(vb1, pf1, oacc[d]);                                      \
    }                                                                           \
    __builtin_amdgcn_s_setprio(0);                                              \
    __syncthreads();                                                            \
    cur ^= 1;                                                                   \
  }

__global__ __launch_bounds__(256, 4) void attn_relu(
    const unsigned short* __restrict__ Q, const unsigned short* __restrict__ Kg,
    const unsigned short* __restrict__ Vt, const unsigned short* __restrict__ Mp,
    unsigned short* __restrict__ O) {
  __shared__ unsigned short KV[2][2][64 * 64];  // [buf][0=K,1=V] 32 KB
  const int tid = threadIdx.x, lane = tid & 63, wid = tid >> 6;
  const int lq = lane & 31, hf = lane >> 5;
  const int qgrp = wid >> 1, cn = wid & 1;
  // XCD-aware swizzle over 1024 blocks: 128 consecutive flats (4 bh) per XCD.
  int flat = blockIdx.y * 32 + blockIdx.x;
  flat = (flat & 7) * 128 + (flat >> 3);
  const int bh = flat >> 5, q0 = (flat & 31) * 64;
  const int b = bh >> 4, hh = bh & 15;
  const int qg = q0 + qgrp * 32 + lq;  // this lane's q row

  // Q B-fragments (col=q, k-elems d = ks*16 + hf*8 + i), straight from global
  const unsigned short* qptr = Q + (size_t)(b * S_LEN + qg) * D_MODEL + hh * DK;
  bfrag8 qf[4];
#pragma unroll
  for (int ks = 0; ks < 4; ++ks)
    qf[ks] = *reinterpret_cast<const bfrag8*>(qptr + ks * 16 + hf * 8);

  // staging: 256 threads; thread t -> tile row p*32 + (t>>3), chunk (t&7)*16
  const int srow = tid >> 3, scb = (tid & 7) * 16;
  const int ssw = scb ^ ((srow & 7) << 4) ^ (((srow >> 3) & 1) << 5);
  const char* kg = (const char*)Kg + ((size_t)(b * S_LEN + srow)) * 2048 + hh * 128 + ssw;
  const char* vg = (const char*)Vt + (size_t)bh * (DK * S_LEN * 2) +
                   (size_t)srow * (S_LEN * 2) + ssw;
  // packed-mask base: elem ((cn*2+hf)*2048 + qg)*16; kt stride = 131072 elems
  const unsigned short* mpb =
      Mp + ((size_t)(cn * 2 + hf) * 2048 + qg) * 16;
  const int swzr = ((lq & 7) << 4) ^ (((lq >> 3) & 1) << 5);  // read-side

  floatx16 oacc[2] = {};

  auto stage = [&](int buf, int kt) {
#pragma unroll
    for (int p = 0; p < 2; ++p) {
      gload16(kg + (size_t)(kt * 64 + p * 32) * 2048,
              (char*)&KV[buf][0][0] + p * 4096 + tid * 16);
      gload16(vg + (size_t)(p * 32) * 4096 + (size_t)kt * 128,
              (char*)&KV[buf][1][0] + p * 4096 + tid * 16);
    }
  };

  stage(0, 0);
  uint4 mkA[2], mkB[2];
  {
    const uint4* m4 = reinterpret_cast<const uint4*>(mpb);
    mkA[0] = m4[0]; mkA[1] = m4[1];
  }
  __syncthreads();

  int cur = 0;
  constexpr int NT = S_LEN / 64;
  for (int kt2 = 0; kt2 < NT; kt2 += 2) {
    ATTN_BODY(kt2, mkA, mkB);
    ATTN_BODY(kt2 + 1, mkB, mkA);
  }

  // ---- combine the two k-halves via LDS (stride 66 f32 -> free 2-way alias)
  float* X = (float*)&KV[0][0][0];  // 64 rows x 66 f32 = 16.9 KB < 32 KB
  const int xrow = (qgrp * 32 + lq) * 66;
  if (cn == 1) {
#pragma unroll
    for (int d = 0; d < 2; ++d)
#pragma unroll
      for (int g = 0; g < 4; ++g) {
        const int off = xrow + d * 32 + 8 * g + 4 * hf;
        float2 lo, hi;
        lo.x = oacc[d][4 * g + 0]; lo.y = oacc[d][4 * g + 1];
        hi.x = oacc[d][4 * g + 2]; hi.y = oacc[d][4 * g + 3];
        *reinterpret_cast<float2*>(&X[off]) = lo;
        *reinterpret_cast<float2*>(&X[off + 2]) = hi;
      }
  }
  __syncthreads();
  if (cn == 0) {
    const size_t obase = (size_t)(b * S_LEN + qg) * D_MODEL + hh * DK;
#pragma unroll
    for (int d = 0; d < 2; ++d)
#pragma unroll
      for (int g = 0; g < 4; ++g) {
        const int off = xrow + d * 32 + 8 * g + 4 * hf;
        float2 lo = *reinterpret_cast<const float2*>(&X[off]);
        float2 hi = *reinterpret_cast<const float2*>(&X[off + 2]);
        float o0 = oacc[d][4 * g + 0] + lo.x;
        float o1 = oacc[d][4 * g + 1] + lo.y;
        float o2 = oacc[d][4 * g + 2] + hi.x;
        float o3 = oacc[d][4 * g + 3] + hi.y;
        uint2 pk;
        pk.x = (unsigned int)f2bf(o0) | ((unsigned int)f2bf(o1) << 16);
        pk.y = (unsigned int)f2bf(o2) | ((unsigned int)f2bf(o3) << 16);
        *reinterpret_cast<uint2*>(&O[obase + d * 32 + 8 * g + 4 * hf]) = pk;
      }
  }
}

extern "C" void kernel_launch(void* const* d_in, const int* in_sizes, int n_in,
                              void* d_out, int out_size, void* d_ws, size_t ws_size,
                              hipStream_t stream) {
  const float* x = (const float*)d_in[0];
  const float* mask = (const float*)d_in[1];
  const float* Wq = (const float*)d_in[2];
  const float* Wk = (const float*)d_in[3];
  const float* Wv = (const float*)d_in[4];
  const float* Wfc = (const float*)d_in[5];
  const float* bfc = (const float*)d_in[6];
  float* out = (float*)d_out;

  char* ws = (char*)d_ws;
  const size_t MB = 1u << 20;
  unsigned short* xb = (unsigned short*)(ws + 0 * MB);     // 8 MB (reused as Ow)
  unsigned short* Wqb = (unsigned short*)(ws + 8 * MB);    // 2 MB
  unsigned short* Wkb = (unsigned short*)(ws + 10 * MB);   // 2 MB
  unsigned short* Wvb = (unsigned short*)(ws + 12 * MB);   // 2 MB
  unsigned short* Wfb = (unsigned short*)(ws + 14 * MB);   // 2 MB
  unsigned short* Qw = (unsigned short*)(ws + 16 * MB);    // 8 MB
  unsigned short* Kw = (unsigned short*)(ws + 24 * MB);    // 8 MB
  unsigned short* Vtw = (unsigned short*)(ws + 32 * MB);   // 8 MB (transposed V)
  unsigned short* Mpw = (unsigned short*)(ws + 48 * MB);   // 8 MB packed mask
  unsigned short* Ow = xb;  // attn runs after QKV GEMMs; xb is dead by then

  // 1 launch: all conversions + bf16 mask pack
  cvt_pack<<<8704, 256, 0, stream>>>(x, Wq, Wk, Wv, Wfc, mask,
                                     xb, Wqb, Wkb, Wvb, Wfb, Mpw);

  // merged Q/K/V projection, TN=64 -> 1536 blocks (6/CU); z==2 (V) writes
  // directly transposed into Vtw
  gemm_nt<0, 64, 1><<<dim3(D_MODEL / 64, (2 * S_LEN) / 128, 3), 256, 0, stream>>>(
      xb, Wqb, Wkb, Wvb, Qw, Kw, Vtw, nullptr, nullptr);

  attn_relu<<<dim3(S_LEN / 64, 32), 256, 0, stream>>>(Qw, Kw, Vtw, Mpw, Ow);

  // FC: 64x64 tiles -> 1024 blocks (4/CU), 2-wave blocks
  gemm_fc64<<<dim3(D_MODEL / 64, (2 * S_LEN) / 64), 128, 0, stream>>>(
      Ow, Wfb, out, bfc);
}

// Round 20
// 125.923 us; speedup vs baseline: 1.1904x; 1.0992x over previous
//
#include <hip/hip_runtime.h>

typedef short bfrag8 __attribute__((ext_vector_type(8)));
typedef float floatx4 __attribute__((ext_vector_type(4)));
typedef float floatx16 __attribute__((ext_vector_type(16)));

#define MFMA_BF16(a, b, c) __builtin_amdgcn_mfma_f32_16x16x32_bf16((a), (b), (c), 0, 0, 0)
#define MFMA32(a, b, c) __builtin_amdgcn_mfma_f32_32x32x16_bf16((a), (b), (c), 0, 0, 0)

#define S_LEN 2048
#define D_MODEL 1024
#define NH 16
#define DK 64

__device__ __forceinline__ unsigned short f2bf(float f) {
  unsigned int u = __float_as_uint(f);
  u += 0x7fffu + ((u >> 16) & 1u);
  return (unsigned short)(u >> 16);
}

typedef const __attribute__((address_space(1))) unsigned int guint;
typedef __attribute__((address_space(3))) unsigned int luint;
__device__ __forceinline__ void gload16(const void* g, void* l) {
  __builtin_amdgcn_global_load_lds((guint*)g, (luint*)l, 16, 0, 0);
}

// ------- fused f32->bf16 conversions + mask pack (bf16), ONE launch ---------
// blocks 0..8191: cvt regions (x 4096 | wq wk wv wfc 1024 each; Wq pre-scaled
// by 0.125 = 1/sqrt(dk)). blocks 8192..8703: pack_mask.
// Mp layout: elem offset (((kt*2 + cn)*2 + hf)*2048 + q)*16 + g*4 + r
// (k = kt*64+cn*32+g*8+hf*4+r) -> attn reads 2 coalesced uint4 per iter.
__global__ __launch_bounds__(256) void cvt_pack(
    const float* __restrict__ x, const float* __restrict__ wq,
    const float* __restrict__ wk, const float* __restrict__ wv,
    const float* __restrict__ wfc, const float* __restrict__ mask,
    unsigned short* __restrict__ xb, unsigned short* __restrict__ wqb,
    unsigned short* __restrict__ wkb, unsigned short* __restrict__ wvb,
    unsigned short* __restrict__ wfb, unsigned short* __restrict__ Mp) {
  __shared__ unsigned short T[64 * 132];
  const int bid = blockIdx.x;
  const int tid = threadIdx.x;
  if (bid < 8192) {
    const float* src;
    unsigned short* dst;
    int base;
    float sc = 1.0f;
    if (bid < 4096) { src = x; dst = xb; base = bid; }
    else if (bid < 5120) { src = wq; dst = wqb; base = bid - 4096; sc = 0.125f; }
    else if (bid < 6144) { src = wk; dst = wkb; base = bid - 5120; }
    else if (bid < 7168) { src = wv; dst = wvb; base = bid - 6144; }
    else { src = wfc; dst = wfb; base = bid - 7168; }
    const int i = (base * 256 + tid) * 4;
    float4 v = *reinterpret_cast<const float4*>(src + i);
    v.x *= sc; v.y *= sc; v.z *= sc; v.w *= sc;
    uint2 p;
    p.x = (unsigned int)f2bf(v.x) | ((unsigned int)f2bf(v.y) << 16);
    p.y = (unsigned int)f2bf(v.z) | ((unsigned int)f2bf(v.w) << 16);
    *reinterpret_cast<uint2*>(dst + i) = p;
    return;
  }
  const int pb = bid - 8192;
  const int kp = pb & 15, qp = pb >> 4;  // 128-k patch, 64-q patch
#pragma unroll
  for (int it = 0; it < 8; ++it) {
    int idx = it * 256 + tid;
    int q = idx >> 5, kq = (idx & 31) * 4;
    float4 v = *reinterpret_cast<const float4*>(
        mask + (size_t)(qp * 64 + q) * 2048 + kp * 128 + kq);
    uint2 p;
    p.x = (unsigned int)f2bf(v.x) | ((unsigned int)f2bf(v.y) << 16);
    p.y = (unsigned int)f2bf(v.z) | ((unsigned int)f2bf(v.w) << 16);
    *reinterpret_cast<uint2*>(&T[q * 132 + kq]) = p;
  }
  __syncthreads();
#pragma unroll
  for (int it = 0; it < 2; ++it) {
    const int item = it * 256 + tid;
    const int q6 = item & 63, rest = item >> 6;
    const int ktl = rest >> 2, cn = (rest >> 1) & 1, hf = rest & 1;
    const int ktg = kp * 2 + ktl;
    const int base = q6 * 132 + ktl * 64 + cn * 32 + hf * 4;
    uint2 u0 = *reinterpret_cast<const uint2*>(&T[base + 0 * 8]);
    uint2 u1 = *reinterpret_cast<const uint2*>(&T[base + 1 * 8]);
    uint2 u2 = *reinterpret_cast<const uint2*>(&T[base + 2 * 8]);
    uint2 u3 = *reinterpret_cast<const uint2*>(&T[base + 3 * 8]);
    unsigned short* dst =
        Mp + ((((size_t)ktg * 2 + cn) * 2 + hf) * 2048 + (qp * 64 + q6)) * 16;
    uint4 w0, w1;
    w0.x = u0.x; w0.y = u0.y; w0.z = u1.x; w0.w = u1.y;
    w1.x = u2.x; w1.y = u2.y; w1.z = u3.x; w1.w = u3.y;
    *reinterpret_cast<uint4*>(dst) = w0;
    *reinterpret_cast<uint4*>(dst + 8) = w1;
  }
}

// ---------------- NT GEMM: C[M,N] = A[M,K] * B[N,K]^T ----------------
// WVT: z==2 (V) output written directly in transposed Vt[bh][dk][S] layout.
// XCD-aware block swizzle (T1): per z-slice, contiguous flats -> one XCD.
template <int WF32, int TN, int WVT>
__global__ __launch_bounds__(256) void gemm_nt(
    const unsigned short* __restrict__ A, const unsigned short* __restrict__ B0,
    const unsigned short* __restrict__ B1, const unsigned short* __restrict__ B2,
    unsigned short* __restrict__ C0, unsigned short* __restrict__ C1,
    unsigned short* __restrict__ C2, float* __restrict__ Cf,
    const float* __restrict__ bias) {
  constexpr int K = 1024;
  constexpr int NJ = TN / 32;  // per-wave N fragments
  __shared__ unsigned short As[2][128 * 32];
  __shared__ unsigned short Bs[2][TN * 32];
  const int z = blockIdx.z;
  const unsigned short* Bw = (z == 0) ? B0 : (z == 1) ? B1 : B2;
  unsigned short* Cb = (z == 0) ? C0 : (z == 1) ? C1 : C2;
  const int tid = threadIdx.x, lane = tid & 63, wid = tid >> 6;
  const int lr = lane & 15, lk = lane >> 4;
  const int gx = gridDim.x, nflat = gx * gridDim.y;
  int flat = blockIdx.y * gx + blockIdx.x;
  flat = (flat & 7) * (nflat >> 3) + (flat >> 3);
  const int bm = (flat / gx) * 128, bn = (flat % gx) * TN;
  const int wm = (wid >> 1) * 64, wn = (wid & 1) * (TN / 2);
  floatx4 acc[4][NJ] = {};

  const int srow = tid >> 2, scb = (tid & 3) * 16;
  const int ssw = scb ^ (((srow >> 1) & 3) << 4);  // pre-swizzled source col
  const char* gA = (const char*)A + ((size_t)(bm + srow) * K) * 2 + ssw;
  const char* gB = (const char*)Bw + ((size_t)(bn + srow) * K) * 2 + ssw;

  auto stage = [&](int buf, int k0) {
    gload16(gA + (size_t)k0 * 2, (char*)&As[buf][0] + tid * 16);
    gload16(gA + ((size_t)64 * K + k0) * 2, (char*)&As[buf][0] + 4096 + tid * 16);
    gload16(gB + (size_t)k0 * 2, (char*)&Bs[buf][0] + tid * 16);
    if constexpr (TN == 128)
      gload16(gB + ((size_t)64 * K + k0) * 2, (char*)&Bs[buf][0] + 4096 + tid * 16);
  };

  stage(0, 0);
  __syncthreads();
  int cur = 0;
  const int csw = (lk * 16) ^ (((lr >> 1) & 3) << 4);  // read-side swizzle
  for (int k0 = 0; k0 < K; k0 += 32) {
    if (k0 + 32 < K) stage(cur ^ 1, k0 + 32);
    const char* Ab = (const char*)&As[cur][0];
    const char* Bb = (const char*)&Bs[cur][0];
    bfrag8 af[4], bfr[NJ];
#pragma unroll
    for (int i = 0; i < 4; ++i)
      af[i] = *reinterpret_cast<const bfrag8*>(Ab + (wm + i * 16 + lr) * 64 + csw);
#pragma unroll
    for (int j = 0; j < NJ; ++j)
      bfr[j] = *reinterpret_cast<const bfrag8*>(Bb + (wn + j * 16 + lr) * 64 + csw);
#pragma unroll
    for (int i = 0; i < 4; ++i)
#pragma unroll
      for (int j = 0; j < NJ; ++j)
        acc[i][j] = MFMA_BF16(af[i], bfr[j], acc[i][j]);
    __syncthreads();
    cur ^= 1;
  }

  if (WVT && z == 2) {
#pragma unroll
    for (int i = 0; i < 4; ++i)
#pragma unroll
      for (int j = 0; j < NJ; ++j) {
        const int row = bm + wm + i * 16 + lk * 4;
        const int col = bn + wn + j * 16 + lr;
        uint2 pk;
        pk.x = (unsigned int)f2bf(acc[i][j][0]) |
               ((unsigned int)f2bf(acc[i][j][1]) << 16);
        pk.y = (unsigned int)f2bf(acc[i][j][2]) |
               ((unsigned int)f2bf(acc[i][j][3]) << 16);
        *reinterpret_cast<uint2*>(
            &Cb[((size_t)(row >> 11) * 1024 + col) * 2048 + (row & 2047)]) = pk;
      }
    return;
  }

#pragma unroll
  for (int i = 0; i < 4; ++i)
#pragma unroll
    for (int j = 0; j < NJ; ++j) {
      const int row = bm + wm + i * 16 + lk * 4;
      const int col = bn + wn + j * 16 + lr;
#pragma unroll
      for (int r = 0; r < 4; ++r) {
        if (WF32)
          Cf[(size_t)(row + r) * D_MODEL + col] = acc[i][j][r] + bias[col];
        else
          Cb[(size_t)(row + r) * D_MODEL + col] = f2bf(acc[i][j][r]);
      }
    }
}

// ---------------- FC GEMM: 64x64 tile, 2 waves, 1024 blocks (4/CU) ----------
__global__ __launch_bounds__(128) void gemm_fc64(
    const unsigned short* __restrict__ A, const unsigned short* __restrict__ Bw,
    float* __restrict__ Cf, const float* __restrict__ bias) {
  constexpr int K = 1024;
  __shared__ unsigned short As[2][64 * 32];
  __shared__ unsigned short Bs[2][64 * 32];
  const int tid = threadIdx.x, lane = tid & 63, wid = tid >> 6;
  const int lr = lane & 15, lk = lane >> 4;
  const int gx = gridDim.x;  // 16
  int flat = blockIdx.y * gx + blockIdx.x;
  flat = (flat & 7) * 128 + (flat >> 3);
  const int bm = (flat / gx) * 64, bn = (flat % gx) * 64;
  const int wm = wid * 32;
  floatx4 acc[2][4] = {};

  const int srow = tid >> 2, scb = (tid & 3) * 16;
  const int ssw = scb ^ (((srow >> 1) & 3) << 4);
  const char* gA = (const char*)A + ((size_t)(bm + srow) * K) * 2 + ssw;
  const char* gB = (const char*)Bw + ((size_t)(bn + srow) * K) * 2 + ssw;

  auto stage = [&](int buf, int k0) {
#pragma unroll
    for (int p = 0; p < 2; ++p) {
      gload16(gA + ((size_t)p * 32 * K + k0) * 2,
              (char*)&As[buf][0] + p * 2048 + tid * 16);
      gload16(gB + ((size_t)p * 32 * K + k0) * 2,
              (char*)&Bs[buf][0] + p * 2048 + tid * 16);
    }
  };

  stage(0, 0);
  __syncthreads();
  int cur = 0;
  const int csw = (lk * 16) ^ (((lr >> 1) & 3) << 4);
  for (int k0 = 0; k0 < K; k0 += 32) {
    if (k0 + 32 < K) stage(cur ^ 1, k0 + 32);
    const char* Ab = (const char*)&As[cur][0];
    const char* Bb = (const char*)&Bs[cur][0];
    bfrag8 af[2], bfr[4];
#pragma unroll
    for (int i = 0; i < 2; ++i)
      af[i] = *reinterpret_cast<const bfrag8*>(Ab + (wm + i * 16 + lr) * 64 + csw);
#pragma unroll
    for (int j = 0; j < 4; ++j)
      bfr[j] = *reinterpret_cast<const bfrag8*>(Bb + (j * 16 + lr) * 64 + csw);
#pragma unroll
    for (int i = 0; i < 2; ++i)
#pragma unroll
      for (int j = 0; j < 4; ++j)
        acc[i][j] = MFMA_BF16(af[i], bfr[j], acc[i][j]);
    __syncthreads();
    cur ^= 1;
  }

#pragma unroll
  for (int i = 0; i < 2; ++i)
#pragma unroll
    for (int j = 0; j < 4; ++j) {
      const int row = bm + wm + i * 16 + lk * 4;
      const int col = bn + j * 16 + lr;
#pragma unroll
      for (int r = 0; r < 4; ++r)
        Cf[(size_t)(row + r) * D_MODEL + col] = acc[i][j][r] + bias[col];
    }
}

// ---------------- fused relu-attention (R15: 4 waves + mask prefetch) --------
// Block = one (b,h) x 64 q; 4 waves = 2 q-groups x 2 k-halves (cn). Grid 1024
// (4 blocks/CU). Mask for kt+1 loads (2 coalesced uint4) while kt computes;
// the end-of-iter barrier drains vmcnt, so the C-init consumes ready regs.
// x2-unrolled bodies with named mask sets (no copies, no runtime reg index).
#define ATTN_BODY(KT, MKU, MKL)                                                 \
  {                                                                             \
    const int kt = (KT);                                                        \
    if (kt + 1 < NT) {                                                          \
      stage(cur ^ 1, kt + 1);                                                   \
      const uint4* m4 = reinterpret_cast<const uint4*>(                         \
          mpb + (size_t)(kt + 1) * 131072);                                     \
      MKL[0] = m4[0]; MKL[1] = m4[1];                                           \
    }                                                                           \
    /* ---- S^T = mask + K^T Q (mask as MFMA C-init; scale folded into Q) */    \
    floatx16 sacc;                                                              \
    sacc[0] = __uint_as_float(MKU[0].x << 16);                                  \
    sacc[1] = __uint_as_float(MKU[0].x & 0xffff0000u);                          \
    sacc[2] = __uint_as_float(MKU[0].y << 16);                                  \
    sacc[3] = __uint_as_float(MKU[0].y & 0xffff0000u);                          \
    sacc[4] = __uint_as_float(MKU[0].z << 16);                                  \
    sacc[5] = __uint_as_float(MKU[0].z & 0xffff0000u);                          \
    sacc[6] = __uint_as_float(MKU[0].w << 16);                                  \
    sacc[7] = __uint_as_float(MKU[0].w & 0xffff0000u);                          \
    sacc[8] = __uint_as_float(MKU[1].x << 16);                                  \
    sacc[9] = __uint_as_float(MKU[1].x & 0xffff0000u);                          \
    sacc[10] = __uint_as_float(MKU[1].y << 16);                                 \
    sacc[11] = __uint_as_float(MKU[1].y & 0xffff0000u);                         \
    sacc[12] = __uint_as_float(MKU[1].z << 16);                                 \
    sacc[13] = __uint_as_float(MKU[1].z & 0xffff0000u);                         \
    sacc[14] = __uint_as_float(MKU[1].w << 16);                                 \
    sacc[15] = __uint_as_float(MKU[1].w & 0xffff0000u);                         \
    const char* Kb = (const char*)&KV[cur][0][0];                               \
    __builtin_amdgcn_s_setprio(1);                                              \
    _Pragma("unroll") for (int ks = 0; ks < 4; ++ks) {                          \
      bfrag8 kf = *reinterpret_cast<const bfrag8*>(                             \
          Kb + (cn * 32 + lq) * 128 + (((ks * 16 + hf * 8) * 2) ^ swzr));       \
      sacc = MFMA32(kf, qf[ks], sacc);                                          \
    }                                                                           \
    __builtin_amdgcn_s_setprio(0);                                              \
    /* ---- relu -> bf16 -> permlane32_swap (P fully in registers) */           \
    float p[16];                                                                \
    _Pragma("unroll") for (int i = 0; i < 16; ++i) p[i] = fmaxf(sacc[i], 0.f);  \
    unsigned int a0, a1, b0, b1, a2, a3, b2, b3;                                \
    asm("v_cvt_pk_bf16_f32 %0, %1, %2" : "=v"(a0) : "v"(p[0]), "v"(p[1]));      \
    asm("v_cvt_pk_bf16_f32 %0, %1, %2" : "=v"(a1) : "v"(p[2]), "v"(p[3]));      \
    asm("v_cvt_pk_bf16_f32 %0, %1, %2" : "=v"(b0) : "v"(p[4]), "v"(p[5]));      \
    asm("v_cvt_pk_bf16_f32 %0, %1, %2" : "=v"(b1) : "v"(p[6]), "v"(p[7]));      \
    asm("v_cvt_pk_bf16_f32 %0, %1, %2" : "=v"(a2) : "v"(p[8]), "v"(p[9]));      \
    asm("v_cvt_pk_bf16_f32 %0, %1, %2" : "=v"(a3) : "v"(p[10]), "v"(p[11]));    \
    asm("v_cvt_pk_bf16_f32 %0, %1, %2" : "=v"(b2) : "v"(p[12]), "v"(p[13]));    \
    asm("v_cvt_pk_bf16_f32 %0, %1, %2" : "=v"(b3) : "v"(p[14]), "v"(p[15]));    \
    asm("v_permlane32_swap_b32 %0, %1" : "+v"(a0), "+v"(b0));                   \
    asm("v_permlane32_swap_b32 %0, %1" : "+v"(a1), "+v"(b1));                   \
    asm("v_permlane32_swap_b32 %0, %1" : "+v"(a2), "+v"(b2));                   \
    asm("v_permlane32_swap_b32 %0, %1" : "+v"(a3), "+v"(b3));                   \
    uint4 u0, u1;                                                               \
    u0.x = a0; u0.y = a1; u0.z = b0; u0.w = b1;                                 \
    u1.x = a2; u1.y = a3; u1.z = b2; u1.w = b3;                                 \
    bfrag8 pf0 = *reinterpret_cast<bfrag8*>(&u0);                               \
    bfrag8 pf1 = *reinterpret_cast<bfrag8*>(&u1);                               \
    const char* Vb = (const char*)&KV[cur][1][0];                               \
    __builtin_amdgcn_s_setprio(1);                                              \
    _Pragma("unroll") for (int d = 0; d < 2; ++d) {                             \
      bfrag8 vb0 = *reinterpret_cast<const bfrag8*>(                            \
          Vb + (d * 32 + lq) * 128 +                                            \
          ((((cn * 2 + 0) * 16 + hf * 8) * 2) ^ swzr));                         \
      oacc[d] = MFMA32(vb0, pf0, oacc[d]);                                      \
      bfrag8 vb1 = *reinterpret_cast<const bfrag8*>(                            \
          Vb + (d * 32 + lq) * 128 +                                            \
          ((((cn * 2 + 1) * 16 + hf * 8) * 2) ^ swzr));                         \
      oacc[d] = MFMA32(vb1, pf1, oacc[d]);                                      \
    }                                                                           \
    __builtin_amdgcn_s_setprio(0);                                              \
    __syncthreads();                                                            \
    cur ^= 1;                                                                   \
  }

__global__ __launch_bounds__(256, 4) void attn_relu(
    const unsigned short* __restrict__ Q, const unsigned short* __restrict__ Kg,
    const unsigned short* __restrict__ Vt, const unsigned short* __restrict__ Mp,
    unsigned short* __restrict__ O) {
  __shared__ unsigned short KV[2][2][64 * 64];  // [buf][0=K,1=V] 32 KB
  const int tid = threadIdx.x, lane = tid & 63, wid = tid >> 6;
  const int lq = lane & 31, hf = lane >> 5;
  const int qgrp = wid >> 1, cn = wid & 1;
  // XCD-aware swizzle over 1024 blocks: 128 consecutive flats (4 bh) per XCD.
  int flat = blockIdx.y * 32 + blockIdx.x;
  flat = (flat & 7) * 128 + (flat >> 3);
  const int bh = flat >> 5, q0 = (flat & 31) * 64;
  const int b = bh >> 4, hh = bh & 15;
  const int qg = q0 + qgrp * 32 + lq;  // this lane's q row

  // Q B-fragments (col=q, k-elems d = ks*16 + hf*8 + i), straight from global
  const unsigned short* qptr = Q + (size_t)(b * S_LEN + qg) * D_MODEL + hh * DK;
  bfrag8 qf[4];
#pragma unroll
  for (int ks = 0; ks < 4; ++ks)
    qf[ks] = *reinterpret_cast<const bfrag8*>(qptr + ks * 16 + hf * 8);

  // staging: 256 threads; thread t -> tile row p*32 + (t>>3), chunk (t&7)*16
  const int srow = tid >> 3, scb = (tid & 7) * 16;
  const int ssw = scb ^ ((srow & 7) << 4) ^ (((srow >> 3) & 1) << 5);
  const char* kg = (const char*)Kg + ((size_t)(b * S_LEN + srow)) * 2048 + hh * 128 + ssw;
  const char* vg = (const char*)Vt + (size_t)bh * (DK * S_LEN * 2) +
                   (size_t)srow * (S_LEN * 2) + ssw;
  // packed-mask base: elem ((cn*2+hf)*2048 + qg)*16; kt stride = 131072 elems
  const unsigned short* mpb =
      Mp + ((size_t)(cn * 2 + hf) * 2048 + qg) * 16;
  const int swzr = ((lq & 7) << 4) ^ (((lq >> 3) & 1) << 5);  // read-side

  floatx16 oacc[2] = {};

  auto stage = [&](int buf, int kt) {
#pragma unroll
    for (int p = 0; p < 2; ++p) {
      gload16(kg + (size_t)(kt * 64 + p * 32) * 2048,
              (char*)&KV[buf][0][0] + p * 4096 + tid * 16);
      gload16(vg + (size_t)(p * 32) * 4096 + (size_t)kt * 128,
              (char*)&KV[buf][1][0] + p * 4096 + tid * 16);
    }
  };

  stage(0, 0);
  uint4 mkA[2], mkB[2];
  {
    const uint4* m4 = reinterpret_cast<const uint4*>(mpb);
    mkA[0] = m4[0]; mkA[1] = m4[1];
  }
  __syncthreads();

  int cur = 0;
  constexpr int NT = S_LEN / 64;
  for (int kt2 = 0; kt2 < NT; kt2 += 2) {
    ATTN_BODY(kt2, mkA, mkB);
    ATTN_BODY(kt2 + 1, mkB, mkA);
  }

  // ---- combine the two k-halves via LDS (stride 66 f32 -> free 2-way alias)
  float* X = (float*)&KV[0][0][0];  // 64 rows x 66 f32 = 16.9 KB < 32 KB
  const int xrow = (qgrp * 32 + lq) * 66;
  if (cn == 1) {
#pragma unroll
    for (int d = 0; d < 2; ++d)
#pragma unroll
      for (int g = 0; g < 4; ++g) {
        const int off = xrow + d * 32 + 8 * g + 4 * hf;
        float2 lo, hi;
        lo.x = oacc[d][4 * g + 0]; lo.y = oacc[d][4 * g + 1];
        hi.x = oacc[d][4 * g + 2]; hi.y = oacc[d][4 * g + 3];
        *reinterpret_cast<float2*>(&X[off]) = lo;
        *reinterpret_cast<float2*>(&X[off + 2]) = hi;
      }
  }
  __syncthreads();
  if (cn == 0) {
    const size_t obase = (size_t)(b * S_LEN + qg) * D_MODEL + hh * DK;
#pragma unroll
    for (int d = 0; d < 2; ++d)
#pragma unroll
      for (int g = 0; g < 4; ++g) {
        const int off = xrow + d * 32 + 8 * g + 4 * hf;
        float2 lo = *reinterpret_cast<const float2*>(&X[off]);
        float2 hi = *reinterpret_cast<const float2*>(&X[off + 2]);
        float o0 = oacc[d][4 * g + 0] + lo.x;
        float o1 = oacc[d][4 * g + 1] + lo.y;
        float o2 = oacc[d][4 * g + 2] + hi.x;
        float o3 = oacc[d][4 * g + 3] + hi.y;
        uint2 pk;
        pk.x = (unsigned int)f2bf(o0) | ((unsigned int)f2bf(o1) << 16);
        pk.y = (unsigned int)f2bf(o2) | ((unsigned int)f2bf(o3) << 16);
        *reinterpret_cast<uint2*>(&O[obase + d * 32 + 8 * g + 4 * hf]) = pk;
      }
  }
}

extern "C" void kernel_launch(void* const* d_in, const int* in_sizes, int n_in,
                              void* d_out, int out_size, void* d_ws, size_t ws_size,
                              hipStream_t stream) {
  const float* x = (const float*)d_in[0];
  const float* mask = (const float*)d_in[1];
  const float* Wq = (const float*)d_in[2];
  const float* Wk = (const float*)d_in[3];
  const float* Wv = (const float*)d_in[4];
  const float* Wfc = (const float*)d_in[5];
  const float* bfc = (const float*)d_in[6];
  float* out = (float*)d_out;

  char* ws = (char*)d_ws;
  const size_t MB = 1u << 20;
  unsigned short* xb = (unsigned short*)(ws + 0 * MB);     // 8 MB (reused as Ow)
  unsigned short* Wqb = (unsigned short*)(ws + 8 * MB);    // 2 MB
  unsigned short* Wkb = (unsigned short*)(ws + 10 * MB);   // 2 MB
  unsigned short* Wvb = (unsigned short*)(ws + 12 * MB);   // 2 MB
  unsigned short* Wfb = (unsigned short*)(ws + 14 * MB);   // 2 MB
  unsigned short* Qw = (unsigned short*)(ws + 16 * MB);    // 8 MB
  unsigned short* Kw = (unsigned short*)(ws + 24 * MB);    // 8 MB
  unsigned short* Vtw = (unsigned short*)(ws + 32 * MB);   // 8 MB (transposed V)
  unsigned short* Mpw = (unsigned short*)(ws + 48 * MB);   // 8 MB packed mask
  unsigned short* Ow = xb;  // attn runs after QKV GEMMs; xb is dead by then

  // 1 launch: all conversions + bf16 mask pack
  cvt_pack<<<8704, 256, 0, stream>>>(x, Wq, Wk, Wv, Wfc, mask,
                                     xb, Wqb, Wkb, Wvb, Wfb, Mpw);

  // merged Q/K/V projection, TN=128 -> 768 blocks (3/CU); z==2 (V) writes
  // directly transposed into Vtw
  gemm_nt<0, 128, 1><<<dim3(D_MODEL / 128, (2 * S_LEN) / 128, 3), 256, 0, stream>>>(
      xb, Wqb, Wkb, Wvb, Qw, Kw, Vtw, nullptr, nullptr);

  attn_relu<<<dim3(S_LEN / 64, 32), 256, 0, stream>>>(Qw, Kw, Vtw, Mpw, Ow);

  // FC: 64x64 tiles -> 1024 blocks (4/CU), 2-wave blocks
  gemm_fc64<<<dim3(D_MODEL / 64, (2 * S_LEN) / 64), 128, 0, stream>>>(
      Ow, Wfb, out, bfc);
}